// Round 19
// baseline (150.604 us; speedup 1.0000x reference)
//
#include <hip/hip_runtime.h>
#include <math.h>

// ---------------------------------------------------------------------------
// S5 dual (fwd+bwd) SSM:  B=4, L=4096, H=1024, P=256
// Pipeline (5 launches):
//   cast_prep: x fp32->bf16 (blocks 0..8191) + build W/CmT/lambda (8192..9727)
//   gemm1:   Zb[16384,1024](bf16) = xbf @ W^T   (256x256 tile, 8 waves)
//            R19: TRUE half-tile 4-phase pipeline (T3/T4): 4 half-buffers per
//            matrix ([dbuf][half] x 128x64 = 16KB each, 128KB LDS). Per K-tile
//            4 phases = 4 M-quadrants x 16 MFMA (setprio). One half-tile
//            (2 gloads) staged per phase AFTER that phase's barrier (slot is
//            dbuf^1 -> never the buffer being read; barrier closes the
//            old-reader window). Counted waits from explicit load-stream
//            accounting: vmcnt(1) @ ph0 (guarantee A-load0s), vmcnt(4) @ ph2
//            (guarantee A-load1s; 4 B-loads of next tile in flight).
//            Last tile: vmcnt(1)/vmcnt(0), no stages. Barriers only ph0/ph2.
//   scanP:   read Zb, local scan in REGISTERS (chunk=64), partials only
//   scanF:   carry inline from partials, SEEDED recurrence -> bf16 xsbf
//   gemm2:   128x128 tile, per-wave 64x64, DUAL acc, counted-vmcnt (R18)
// Ledger: R5 dbuf+syncthreads X; R6 32x32 X; R9 lookback atomics X;
// R14 reg-stash spill X; R15 K-split X; R16 chunk32 X; R17 coarse phase-lock
// X (m196 hurt-variant; THIS round adds the missing fine interleave).
// Column layout (inner 1024): c = dir*512 + 2*p + comp  (comp: 0=re, 1=im)
// XOR swizzle (T2) both-sides (rule #21): row&7 == (tid>>3)&7 == fr&7
// invariants hold for all stage/read mappings. Conflicts == 0 (R2..R18).
// ---------------------------------------------------------------------------

typedef short bf16x8 __attribute__((ext_vector_type(8)));
typedef float f32x4 __attribute__((ext_vector_type(4)));
typedef unsigned short u16x8 __attribute__((ext_vector_type(8)));

__device__ __forceinline__ unsigned short f2bf(float f) {
  union { float f; unsigned int u; } v; v.f = f;
  unsigned int r = (v.u + 0x7FFFu + ((v.u >> 16) & 1u)) >> 16;
  return (unsigned short)r;
}
__device__ __forceinline__ float bf2f(unsigned short s) {
  union { unsigned int u; float f; } v; v.u = ((unsigned int)s) << 16;
  return v.f;
}
// tanh-form gelu via sigmoid: gelu(v) ~= v * sigmoid(1.5957691*(v+0.044715 v^3))
__device__ __forceinline__ float gelu_fast(float v) {
  const float u = 1.5957691216057308f * fmaf(0.044715f * v, v * v, v);
  return v / (1.f + __expf(-u));
}
__device__ __forceinline__ void gload16(const unsigned short* g, void* l) {
  __builtin_amdgcn_global_load_lds(
      (const __attribute__((address_space(1))) void*)g,
      (__attribute__((address_space(3))) void*)l, 16, 0, 0);
}

// --------------------- fused cast_x + prep ----------------------------------
__global__ __launch_bounds__(256) void cast_prep_kernel(
    const float* __restrict__ x, unsigned short* __restrict__ xbf,
    const float* __restrict__ flr, const float* __restrict__ fim,
    const float* __restrict__ fBr, const float* __restrict__ fBi,
    const float* __restrict__ fCr, const float* __restrict__ fCi,
    const float* __restrict__ flD,
    const float* __restrict__ blr, const float* __restrict__ bim,
    const float* __restrict__ bBr, const float* __restrict__ bBi,
    const float* __restrict__ bCr, const float* __restrict__ bCi,
    const float* __restrict__ blD,
    unsigned short* __restrict__ W, unsigned short* __restrict__ CmT,
    float4* __restrict__ lamp) {
  const int tid = threadIdx.x;
  if (blockIdx.x < 8192) {  // -------- cast path: 8 floats/thread
    const size_t i = (size_t)blockIdx.x * 256 + tid;
    const float4* xv = (const float4*)x;
    float4 a = xv[2 * i], b = xv[2 * i + 1];
    u16x8 r;
    r[0] = f2bf(a.x); r[1] = f2bf(a.y); r[2] = f2bf(a.z); r[3] = f2bf(a.w);
    r[4] = f2bf(b.x); r[5] = f2bf(b.y); r[6] = f2bf(b.z); r[7] = f2bf(b.w);
    *(u16x8*)(xbf + 8 * i) = r;
    return;
  }
  const int bid = blockIdx.x - 8192;  // -------- prep path (0..1535)
  if (bid < 512) {
    const int dir = bid >> 8, p = bid & 255;
    const float* lr_ = dir ? blr : flr;
    const float* im_ = dir ? bim : fim;
    const float* lD_ = dir ? blD : flD;
    const float* Br_ = dir ? bBr : fBr;
    const float* Bi_ = dir ? bBi : fBi;
    const float Lre = -expf(lr_[p]);
    const float Lim = im_[p];
    const float Dl = expf(lD_[p]);
    const float ar = Lre * Dl, ai = Lim * Dl;
    const float er = expf(ar);
    const float lre = er * cosf(ai), lim = er * sinf(ai);
    const float e64 = expf(64.f * ar);
    const float l64re = e64 * cosf(64.f * ai), l64im = e64 * sinf(64.f * ai);
    float sre = Lre, sim = Lim;
    if (sqrtf(Lre * Lre + Lim * Lim) < 1e-6f) { sre = 1e-6f; sim = 0.f; }
    const float den = sre * sre + sim * sim;
    const float fre = ((lre - 1.f) * sre + lim * sim) / den;
    const float fi2 = (lim * sre - (lre - 1.f) * sim) / den;
    if (tid == 0) lamp[dir * 256 + p] = make_float4(lre, lim, l64re, l64im);
    const size_t rowR = (size_t)(dir * 512 + 2 * p) * 1024;
    const size_t rowI = rowR + 1024;
    for (int h = tid; h < 1024; h += 256) {
      const float Br = Br_[p * 1024 + h], Bi = Bi_[p * 1024 + h];
      W[rowR + h] = f2bf(fre * Br - fi2 * Bi);
      W[rowI + h] = f2bf(fre * Bi + fi2 * Br);
    }
  } else {
    const int h = bid - 512;
    for (int k = tid; k < 1024; k += 256) {
      const int dir = k >> 9, within = k & 511;
      const int p = within >> 1, comp = within & 1;
      const float* C = comp ? (dir ? bCi : fCi) : (dir ? bCr : fCr);
      float v = C[(size_t)h * 256 + p];
      if (comp) v = -v;
      CmT[(size_t)h * 1024 + k] = f2bf(v);
    }
  }
}

// =================== GEMM1 (256^2, 8 waves, half-tile 4-phase) ==============
// Zb[m][c] = bf16( sum_h xbf[m][h] * W[c][h] );  M=16384, N=1024, K=1024
// LDS: As/Bs = 4 half-buffers each of [128][64] bf16 (16KB); slot=(dbuf<<1)|half.
// Stage one half-tile (2 gloads/thread): rows H*128 + i*64 + (tid>>3),
// linear LDS dest, swizzled global source column csw.
#define G1_SA(DBUF, H, KT)                                                     \
  {                                                                            \
    _Pragma("unroll") for (int i = 0; i < 2; ++i) {                            \
      const int rh = ((H) << 7) + (i << 6) + tr;                               \
      const int o = ((((DBUF) << 1) | (H)) << 14) + (i << 13) + (tid << 4);    \
      gload16(xbf + (size_t)(m0 + rh) * 1024 + ((KT) << 6) + csw,              \
              (char*)As + o);                                                  \
    }                                                                          \
  }
#define G1_SB(DBUF, H, KT)                                                     \
  {                                                                            \
    _Pragma("unroll") for (int i = 0; i < 2; ++i) {                            \
      const int rh = ((H) << 7) + (i << 6) + tr;                               \
      const int o = ((((DBUF) << 1) | (H)) << 14) + (i << 13) + (tid << 4);    \
      gload16(W + (size_t)(n0 + rh) * 1024 + ((KT) << 6) + csw,                \
              (char*)Bs + o);                                                  \
    }                                                                          \
  }

// One quadrant phase: 4 aF ds_reads + 16 MFMA (setprio-wrapped).
#define G1_PHASE(PH, D, ACC)                                                   \
  {                                                                            \
    bf16x8 aF[2][2];                                                           \
    _Pragma("unroll") for (int mf2 = 0; mf2 < 2; ++mf2)                        \
        _Pragma("unroll") for (int kk2 = 0; kk2 < 2; ++kk2) {                  \
      const int rowh = ((PH) << 5) + (mf2 << 4) + fr;                          \
      aF[mf2][kk2] = *(const bf16x8*)&As[((((D) << 1) | wm) << 13) +           \
                                         rowh * 64 + (((kk2 << 5) + ks) ^ sw)];\
    }                                                                          \
    __builtin_amdgcn_s_setprio(1);                                             \
    _Pragma("unroll") for (int mf2 = 0; mf2 < 2; ++mf2)                        \
        _Pragma("unroll") for (int n4 = 0; n4 < 4; ++n4)                       \
            _Pragma("unroll") for (int kk2 = 0; kk2 < 2; ++kk2)                \
                ACC[((PH) << 1) + mf2][n4] =                                   \
                    __builtin_amdgcn_mfma_f32_16x16x32_bf16(                   \
                        aF[mf2][kk2], bF[n4][kk2], ACC[((PH) << 1) + mf2][n4], \
                        0, 0, 0);                                              \
    __builtin_amdgcn_s_setprio(0);                                             \
  }

__global__ __launch_bounds__(512, 2) void gemm1_kernel(
    const unsigned short* __restrict__ xbf, const unsigned short* __restrict__ W,
    unsigned short* __restrict__ Zb) {
  __shared__ unsigned short As[4 * 128 * 64];  // 64 KB (4 half-buffers)
  __shared__ unsigned short Bs[4 * 128 * 64];  // 64 KB
  const int tid = threadIdx.x;
  const int lane = tid & 63;
  const int w = tid >> 6;                    // 0..7
  const int wm = w >> 2, wn = w & 3;         // 2M x 4N
  const int fr = lane & 15;
  const int ks = (lane >> 4) << 3;
  const int sw = (fr & 7) << 3;              // ds_read XOR (elements)
  const int tr = tid >> 3;                   // staging row-within-64 (0..63)
  const int csw = ((tid & 7) ^ (tr & 7)) << 3;  // staging src col (elems)
  const int bsw = ((blockIdx.x & 7) << 5) + (blockIdx.x >> 3);  // XCD swizzle
  const int nt = bsw & 3, mt = bsw >> 2;     // 4 N-tiles, 64 M-tiles
  const int m0 = mt << 8, n0 = nt << 8;

  f32x4 acc[8][4] = {};

  // Prologue: tile 0's four halves in canonical order B_top,B_bot,A_top,A_bot.
  G1_SB(0, 0, 0); G1_SB(0, 1, 0); G1_SA(0, 0, 0); G1_SA(0, 1, 0);

  for (int kt = 0; kt < 16; ++kt) {
    const int d = kt & 1, dn = d ^ 1;
    bf16x8 bF[4][2];
    // -------- ph0: wait (B(t) full + A load0s), barrier, stage B_top(t+1)
    asm volatile("s_waitcnt vmcnt(1)" ::: "memory");
    __builtin_amdgcn_sched_barrier(0);
    __builtin_amdgcn_s_barrier();
    asm volatile("" ::: "memory");
    __builtin_amdgcn_sched_barrier(0);
    if (kt < 15) G1_SB(dn, 0, kt + 1);
    // B-frags for the whole tile (8 ds_reads), then quadrant 0
#pragma unroll
    for (int n4 = 0; n4 < 4; ++n4)
#pragma unroll
      for (int kk2 = 0; kk2 < 2; ++kk2) {
        const int rowh = ((wn & 1) << 6) + (n4 << 4) + fr;
        bF[n4][kk2] = *(const bf16x8*)&Bs[(((d << 1) | (wn >> 1)) << 13) +
                                          rowh * 64 + (((kk2 << 5) + ks) ^ sw)];
      }
    G1_PHASE(0, d, acc);
    // -------- ph1: stage B_bot(t+1), quadrant 1 (rows 32..63 = load0, safe)
    if (kt < 15) G1_SB(dn, 1, kt + 1);
    G1_PHASE(1, d, acc);
    // -------- ph2: wait (A load1s), barrier, stage A_top(t+1)
    if (kt < 15) {
      asm volatile("s_waitcnt vmcnt(4)" ::: "memory");
    } else {
      asm volatile("s_waitcnt vmcnt(0)" ::: "memory");
    }
    __builtin_amdgcn_sched_barrier(0);
    __builtin_amdgcn_s_barrier();
    asm volatile("" ::: "memory");
    __builtin_amdgcn_sched_barrier(0);
    if (kt < 15) G1_SA(dn, 0, kt + 1);
    G1_PHASE(2, d, acc);
    // -------- ph3: stage A_bot(t+1), quadrant 3
    if (kt < 15) G1_SA(dn, 1, kt + 1);
    G1_PHASE(3, d, acc);
  }

  const int rb = (lane >> 4) << 2;
#pragma unroll
  for (int mf = 0; mf < 8; ++mf)
#pragma unroll
    for (int n4 = 0; n4 < 4; ++n4) {
      const size_t gn = n0 + (wn << 6) + (n4 << 4) + fr;
#pragma unroll
      for (int r = 0; r < 4; ++r) {
        const size_t gm = m0 + (wm << 7) + (mf << 4) + rb + r;
        Zb[gm * 1024 + gn] = f2bf(acc[mf][n4][r]);
      }
    }
}

// ------------------------------- scanP --------------------------------------
// Zb viewed as u32 pairs: Zp[m][512], col = dir*256 + p, packed (re, im) bf16.
// Block = s*64 + k (s = b*2+dir). Local scan in REGISTERS (no write-back);
// emit only the chunk-final state to part[s][k][p].
__global__ __launch_bounds__(256) void scanP_kernel(
    const unsigned int* __restrict__ Zp, const float4* __restrict__ lamp,
    float2* __restrict__ part) {
  const int p = threadIdx.x;
  const int k = blockIdx.x & 63;
  const int s = blockIdx.x >> 6;
  const int dir = s & 1, b = s >> 1;
  const float4 lp = lamp[dir * 256 + p];
  const float lre = lp.x, lim = lp.y;
  const size_t col = (size_t)dir * 256 + p;
  const size_t mbase = (size_t)b * 4096 + (size_t)k * 64;
  float sre = 0.f, sim = 0.f;
  if (dir == 0) {
    for (int i = 0; i < 64; ++i) {
      const unsigned int u = Zp[(mbase + i) * 512 + col];
      const float nr = fmaf(lre, sre, fmaf(-lim, sim, bf2f((unsigned short)u)));
      const float ni = fmaf(lre, sim, fmaf(lim, sre, bf2f((unsigned short)(u >> 16))));
      sre = nr; sim = ni;
    }
  } else {
    for (int i = 63; i >= 0; --i) {
      const unsigned int u = Zp[(mbase + i) * 512 + col];
      const float nr = fmaf(lre, sre, fmaf(-lim, sim, bf2f((unsigned short)u)));
      const float ni = fmaf(lre, sim, fmaf(lim, sre, bf2f((unsigned short)(u >> 16))));
      sre = nr; sim = ni;
    }
  }
  part[(size_t)(s * 64 + k) * 256 + p] = make_float2(sre, sim);
}

// ------------------------------- scanF --------------------------------------
// Carry inline from partials (direction-aware weights), then SEEDED
// recurrence over the chunk: s_{-1} = C;  s_i = lambda*s_{i-1} + u_i;
// write bf16-packed xs. (== loc_i + lambda^(i+1) C algebraically.)
__global__ __launch_bounds__(256) void scanF_kernel(
    const unsigned int* __restrict__ Zp, const float4* __restrict__ lamp,
    const float2* __restrict__ part, unsigned int* __restrict__ xsbf) {
  const int p = threadIdx.x;
  const int k = blockIdx.x & 63;
  const int s = blockIdx.x >> 6;
  const int dir = s & 1, b = s >> 1;
  const float4 lp = lamp[dir * 256 + p];
  const float lre = lp.x, lim = lp.y, wr64 = lp.z, wi64 = lp.w;
  const size_t col = (size_t)dir * 256 + p;
  const size_t mbase = (size_t)b * 4096 + (size_t)k * 64;

  // exclusive carry:
  //   fwd: C = sum_{j<k} l64^(k-1-j) S_j   (j descending, w starts at 1)
  //   bwd: C = sum_{j>k} l64^(j-k-1) S_j   (j ascending,  w starts at 1)
  float cr = 0.f, ci = 0.f, wr = 1.f, wi = 0.f;
  if (dir == 0) {
    for (int j = k - 1; j >= 0; --j) {
      const float2 S = part[(size_t)(s * 64 + j) * 256 + p];
      cr = fmaf(wr, S.x, fmaf(-wi, S.y, cr));
      ci = fmaf(wr, S.y, fmaf(wi, S.x, ci));
      const float t = wr * wr64 - wi * wi64;
      wi = wr * wi64 + wi * wr64; wr = t;
    }
  } else {
    for (int j = k + 1; j < 64; ++j) {
      const float2 S = part[(size_t)(s * 64 + j) * 256 + p];
      cr = fmaf(wr, S.x, fmaf(-wi, S.y, cr));
      ci = fmaf(wr, S.y, fmaf(wi, S.x, ci));
      const float t = wr * wr64 - wi * wi64;
      wi = wr * wi64 + wi * wr64; wr = t;
    }
  }

  float sre = cr, sim = ci;  // state entering the chunk
  if (dir == 0) {
    for (int i = 0; i < 64; ++i) {
      const size_t idx = (mbase + i) * 512 + col;
      const unsigned int u = Zp[idx];
      const float nr = fmaf(lre, sre, fmaf(-lim, sim, bf2f((unsigned short)u)));
      const float ni = fmaf(lre, sim, fmaf(lim, sre, bf2f((unsigned short)(u >> 16))));
      sre = nr; sim = ni;
      xsbf[idx] = (unsigned int)f2bf(sre) | ((unsigned int)f2bf(sim) << 16);
    }
  } else {
    for (int i = 63; i >= 0; --i) {
      const size_t idx = (mbase + i) * 512 + col;
      const unsigned int u = Zp[idx];
      const float nr = fmaf(lre, sre, fmaf(-lim, sim, bf2f((unsigned short)u)));
      const float ni = fmaf(lre, sim, fmaf(lim, sre, bf2f((unsigned short)(u >> 16))));
      sre = nr; sim = ni;
      xsbf[idx] = (unsigned int)f2bf(sre) | ((unsigned int)f2bf(sim) << 16);
    }
  }
}

// ------------------- GEMM2 (128^2, dual acc, counted vmcnt) ------------------
#define GEMM_STAGE(BUF, KT, APTR, BPTR)                                        \
  {                                                                            \
    const int k0 = (KT) << 6;                                                  \
    _Pragma("unroll") for (int i = 0; i < 4; ++i) {                            \
      const int r = (i << 5) + tr2;                                            \
      const int o = ((BUF) << 14) + (i << 12) + (tid << 4);                    \
      gload16(APTR + (size_t)(m0 + r) * 1024 + (k0 + csw), (char*)As + o);     \
      gload16(BPTR + (size_t)(n0 + r) * 1024 + (k0 + csw), (char*)Bs + o);     \
    }                                                                          \
  }

#define PIPE_PUBLISH8()                                                        \
  asm volatile("s_waitcnt vmcnt(8)" ::: "memory");                             \
  __builtin_amdgcn_sched_barrier(0);                                           \
  __builtin_amdgcn_s_barrier();                                                \
  __builtin_amdgcn_sched_barrier(0);

#define PIPE_CLOSE()                                                           \
  __builtin_amdgcn_sched_barrier(0);                                           \
  __builtin_amdgcn_s_barrier();                                                \
  __builtin_amdgcn_sched_barrier(0);

#define GEMM_COMPUTE(BUF, ACC)                                                 \
  {                                                                            \
    const int bo = (BUF) << 13; /* element offset within As/Bs */              \
    _Pragma("unroll") for (int kk = 0; kk < 64; kk += 32) {                    \
      bf16x8 af[4], bf_[4];                                                    \
      _Pragma("unroll") for (int m4 = 0; m4 < 4; ++m4) {                       \
        const int row = (wm << 6) + (m4 << 4) + fr;                            \
        af[m4] = *(const bf16x8*)&As[bo + row * 64 + ((kk + ks) ^ sw)];        \
      }                                                                        \
      _Pragma("unroll") for (int n4 = 0; n4 < 4; ++n4) {                       \
        const int row = (wn << 6) + (n4 << 4) + fr;                            \
        bf_[n4] = *(const bf16x8*)&Bs[bo + row * 64 + ((kk + ks) ^ sw)];       \
      }                                                                        \
      _Pragma("unroll") for (int m4 = 0; m4 < 4; ++m4)                         \
          _Pragma("unroll") for (int n4 = 0; n4 < 4; ++n4)                     \
              ACC[m4][n4] = __builtin_amdgcn_mfma_f32_16x16x32_bf16(           \
                  af[m4], bf_[n4], ACC[m4][n4], 0, 0, 0);                      \
    }                                                                          \
  }

__global__ __launch_bounds__(256, 2) void gemm2_kernel(
    const unsigned short* __restrict__ A2, const unsigned short* __restrict__ CmT,
    const unsigned short* __restrict__ xbf, const float* __restrict__ Df,
    const float* __restrict__ Db, float* __restrict__ out) {
  __shared__ unsigned short As[2 * 128 * 64];
  __shared__ unsigned short Bs[2 * 128 * 64];
  const int tid = threadIdx.x;
  const int lane = tid & 63;
  const int w = tid >> 6;
  const int wm = w >> 1, wn = w & 1;
  const int fr = lane & 15;
  const int ks = (lane >> 4) << 3;
  const int sw = (fr & 7) << 3;
  const int tr2 = tid >> 3;
  const int csw = ((tid & 7) ^ (tr2 & 7)) << 3;
  const int bsw = ((blockIdx.x & 7) << 7) + (blockIdx.x >> 3);  // XCD swizzle
  const int nt = bsw & 7, mt = bsw >> 3;
  const int m0 = mt << 7, n0 = nt << 7;

  f32x4 accf[4][4] = {};
  f32x4 accb[4][4] = {};

  GEMM_STAGE(0, 0, A2, CmT);
  int cur = 0;
#pragma unroll
  for (int kt = 0; kt < 8; ++kt) {
    GEMM_STAGE(cur ^ 1, kt + 1, A2, CmT);
    PIPE_PUBLISH8();
    GEMM_COMPUTE(cur, accf);
    PIPE_CLOSE();
    cur ^= 1;
  }
#pragma unroll
  for (int kt = 8; kt < 15; ++kt) {
    GEMM_STAGE(cur ^ 1, kt + 1, A2, CmT);
    PIPE_PUBLISH8();
    GEMM_COMPUTE(cur, accb);
    PIPE_CLOSE();
    cur ^= 1;
  }
  __syncthreads();                         // final tile: full drain ok here
  GEMM_COMPUTE(cur, accb);

  const int rb = (lane >> 4) << 2;
#pragma unroll
  for (int n4 = 0; n4 < 4; ++n4) {
    const size_t gn = n0 + (wn << 6) + (n4 << 4) + fr;
    const float dfv = Df[gn], dbv = Db[gn];
#pragma unroll
    for (int m4 = 0; m4 < 4; ++m4) {
#pragma unroll
      for (int r = 0; r < 4; ++r) {
        const size_t gm = m0 + (wm << 6) + (m4 << 4) + rb + r;
        const float xv = bf2f(xbf[gm * 1024 + gn]);
        out[gm * 1024 + gn] = gelu_fast(accf[m4][n4][r] + dfv * xv) +
                              gelu_fast(accb[m4][n4][r] + dbv * xv);
      }
    }
  }
}

// ------------------------------- launch -------------------------------------
extern "C" void kernel_launch(void* const* d_in, const int* in_sizes, int n_in,
                              void* d_out, int out_size, void* d_ws, size_t ws_size,
                              hipStream_t stream) {
  const float* x = (const float*)d_in[0];
  const float* flr = (const float*)d_in[1];
  const float* fim = (const float*)d_in[2];
  const float* fBr = (const float*)d_in[3];
  const float* fBi = (const float*)d_in[4];
  const float* fCr = (const float*)d_in[5];
  const float* fCi = (const float*)d_in[6];
  const float* fD  = (const float*)d_in[7];
  const float* flD = (const float*)d_in[8];
  const float* blr = (const float*)d_in[9];
  const float* bim = (const float*)d_in[10];
  const float* bBr = (const float*)d_in[11];
  const float* bBi = (const float*)d_in[12];
  const float* bCr = (const float*)d_in[13];
  const float* bCi = (const float*)d_in[14];
  const float* bD  = (const float*)d_in[15];
  const float* blD = (const float*)d_in[16];

  char* ws = (char*)d_ws;
  unsigned short* xbf  = (unsigned short*)(ws);                  // 33,554,432
  unsigned short* W    = (unsigned short*)(ws + 33554432);       //  2,097,152
  unsigned short* CmT  = (unsigned short*)(ws + 35651584);       //  2,097,152
  unsigned short* Zb   = (unsigned short*)(ws + 37748736);       // 33,554,432
  unsigned short* xsbf = (unsigned short*)(ws + 71303168);       // 33,554,432
  float4*         lamp = (float4*)(ws + 104857600);              //      8,192
  float2*         part = (float2*)(ws + 104865792);              //  1,048,576

  cast_prep_kernel<<<9728, 256, 0, stream>>>(
      x, xbf, flr, fim, fBr, fBi, fCr, fCi, flD,
      blr, bim, bBr, bBi, bCr, bCi, blD, W, CmT, lamp);
  gemm1_kernel<<<256, 512, 0, stream>>>(xbf, W, Zb);
  scanP_kernel<<<512, 256, 0, stream>>>((unsigned int*)Zb, lamp, part);
  scanF_kernel<<<512, 256, 0, stream>>>((unsigned int*)Zb, lamp, part,
                                        (unsigned int*)xsbf);
  gemm2_kernel<<<1024, 256, 0, stream>>>(xsbf, CmT, xbf, fD, bD, (float*)d_out);
}

// Round 20
// 134.979 us; speedup vs baseline: 1.1158x; 1.1158x over previous
//
#include <hip/hip_runtime.h>
#include <math.h>

// ---------------------------------------------------------------------------
// S5 dual (fwd+bwd) SSM:  B=4, L=4096, H=1024, P=256
// Pipeline (4 launches):
//   cast_prep: x fp32->bf16 (blocks 0..8191) + build W/CmT/lambda (8192..9727)
//   gemm1:   256x256 tile, 8 waves, counted-vmcnt (R18 loop).  R20: epilogue
//            FUSES scanP -- acc spilled as bf16 into the (dead) 128KB staging
//            LDS, each thread scans one (chunk, colpair): 64 rows, writes
//            LOCAL-SCANNED bf16 values to Zb + chunk partial. Same rounding
//            as the old Zb write -> scan inputs bit-identical to old scanP.
//   scanF:   carry inline from partials (direction-aware weights), FIXUP form
//            xs_i = loc_i + lambda^(i+1)*C (verbatim R10 scanC walk).
//   gemm2:   128x128 tile, per-wave 64x64, DUAL acc, counted-vmcnt (R18).
// Ledger: R5 dbuf+syncthreads X; R6 32x32 X; R9 lookback atomics X;
// R14 reg-stash spill X; R15 K-split X; R16 chunk32 X; R17 coarse phase-lock
// X; R19 half-tile 4-phase X (9 sync-structure attempts -> R18 is the local
// optimum; this round removes HBM traffic instead).
// Column layout (inner 1024): c = dir*512 + 2*p + comp  (comp: 0=re, 1=im)
// XOR swizzle (T2) both-sides (rule #21). GEMM LDS conflicts == 0.
// ---------------------------------------------------------------------------

typedef short bf16x8 __attribute__((ext_vector_type(8)));
typedef float f32x4 __attribute__((ext_vector_type(4)));
typedef unsigned short u16x8 __attribute__((ext_vector_type(8)));

__device__ __forceinline__ unsigned short f2bf(float f) {
  union { float f; unsigned int u; } v; v.f = f;
  unsigned int r = (v.u + 0x7FFFu + ((v.u >> 16) & 1u)) >> 16;
  return (unsigned short)r;
}
__device__ __forceinline__ float bf2f(unsigned short s) {
  union { unsigned int u; float f; } v; v.u = ((unsigned int)s) << 16;
  return v.f;
}
// tanh-form gelu via sigmoid: gelu(v) ~= v * sigmoid(1.5957691*(v+0.044715 v^3))
__device__ __forceinline__ float gelu_fast(float v) {
  const float u = 1.5957691216057308f * fmaf(0.044715f * v, v * v, v);
  return v / (1.f + __expf(-u));
}
__device__ __forceinline__ void gload16(const unsigned short* g, void* l) {
  __builtin_amdgcn_global_load_lds(
      (const __attribute__((address_space(1))) void*)g,
      (__attribute__((address_space(3))) void*)l, 16, 0, 0);
}

// --------------------- fused cast_x + prep ----------------------------------
__global__ __launch_bounds__(256) void cast_prep_kernel(
    const float* __restrict__ x, unsigned short* __restrict__ xbf,
    const float* __restrict__ flr, const float* __restrict__ fim,
    const float* __restrict__ fBr, const float* __restrict__ fBi,
    const float* __restrict__ fCr, const float* __restrict__ fCi,
    const float* __restrict__ flD,
    const float* __restrict__ blr, const float* __restrict__ bim,
    const float* __restrict__ bBr, const float* __restrict__ bBi,
    const float* __restrict__ bCr, const float* __restrict__ bCi,
    const float* __restrict__ blD,
    unsigned short* __restrict__ W, unsigned short* __restrict__ CmT,
    float4* __restrict__ lamp) {
  const int tid = threadIdx.x;
  if (blockIdx.x < 8192) {  // -------- cast path: 8 floats/thread
    const size_t i = (size_t)blockIdx.x * 256 + tid;
    const float4* xv = (const float4*)x;
    float4 a = xv[2 * i], b = xv[2 * i + 1];
    u16x8 r;
    r[0] = f2bf(a.x); r[1] = f2bf(a.y); r[2] = f2bf(a.z); r[3] = f2bf(a.w);
    r[4] = f2bf(b.x); r[5] = f2bf(b.y); r[6] = f2bf(b.z); r[7] = f2bf(b.w);
    *(u16x8*)(xbf + 8 * i) = r;
    return;
  }
  const int bid = blockIdx.x - 8192;  // -------- prep path (0..1535)
  if (bid < 512) {
    const int dir = bid >> 8, p = bid & 255;
    const float* lr_ = dir ? blr : flr;
    const float* im_ = dir ? bim : fim;
    const float* lD_ = dir ? blD : flD;
    const float* Br_ = dir ? bBr : fBr;
    const float* Bi_ = dir ? bBi : fBi;
    const float Lre = -expf(lr_[p]);
    const float Lim = im_[p];
    const float Dl = expf(lD_[p]);
    const float ar = Lre * Dl, ai = Lim * Dl;
    const float er = expf(ar);
    const float lre = er * cosf(ai), lim = er * sinf(ai);
    const float e64 = expf(64.f * ar);
    const float l64re = e64 * cosf(64.f * ai), l64im = e64 * sinf(64.f * ai);
    float sre = Lre, sim = Lim;
    if (sqrtf(Lre * Lre + Lim * Lim) < 1e-6f) { sre = 1e-6f; sim = 0.f; }
    const float den = sre * sre + sim * sim;
    const float fre = ((lre - 1.f) * sre + lim * sim) / den;
    const float fi2 = (lim * sre - (lre - 1.f) * sim) / den;
    if (tid == 0) lamp[dir * 256 + p] = make_float4(lre, lim, l64re, l64im);
    const size_t rowR = (size_t)(dir * 512 + 2 * p) * 1024;
    const size_t rowI = rowR + 1024;
    for (int h = tid; h < 1024; h += 256) {
      const float Br = Br_[p * 1024 + h], Bi = Bi_[p * 1024 + h];
      W[rowR + h] = f2bf(fre * Br - fi2 * Bi);
      W[rowI + h] = f2bf(fre * Bi + fi2 * Br);
    }
  } else {
    const int h = bid - 512;
    for (int k = tid; k < 1024; k += 256) {
      const int dir = k >> 9, within = k & 511;
      const int p = within >> 1, comp = within & 1;
      const float* C = comp ? (dir ? bCi : fCi) : (dir ? bCr : fCr);
      float v = C[(size_t)h * 256 + p];
      if (comp) v = -v;
      CmT[(size_t)h * 1024 + k] = f2bf(v);
    }
  }
}

// ----------------- shared 256^2 / 8-wave stage & sync macros ----------------
#define G256_STAGE(BUF, KT, APTR, BPTR)                                        \
  {                                                                            \
    const int k0 = (KT) << 6;                                                  \
    _Pragma("unroll") for (int i = 0; i < 4; ++i) {                            \
      const int r = (i << 6) + tr;                                             \
      const int o = ((BUF) << 15) + (i << 13) + (tid << 4);                    \
      gload16(APTR + (size_t)(m0 + r) * 1024 + (k0 + csw), (char*)As + o);     \
      gload16(BPTR + (size_t)(n0 + r) * 1024 + (k0 + csw), (char*)Bs + o);     \
    }                                                                          \
  }

#define PIPE_PUBLISH8()                                                        \
  asm volatile("s_waitcnt vmcnt(8)" ::: "memory");                             \
  __builtin_amdgcn_sched_barrier(0);                                           \
  __builtin_amdgcn_s_barrier();                                                \
  __builtin_amdgcn_sched_barrier(0);

#define PIPE_CLOSE()                                                           \
  __builtin_amdgcn_sched_barrier(0);                                           \
  __builtin_amdgcn_s_barrier();                                                \
  __builtin_amdgcn_sched_barrier(0);

// 256^2 compute: B-frags [4][2] upfront (reused over 4 sub-phases of 16 MFMA,
// each setprio-wrapped).
#define G1_COMPUTE(BUF, ACC)                                                   \
  {                                                                            \
    const int bo = (BUF) << 14; /* element offset */                           \
    bf16x8 bF[4][2];                                                           \
    _Pragma("unroll") for (int n4 = 0; n4 < 4; ++n4)                           \
        _Pragma("unroll") for (int kk2 = 0; kk2 < 2; ++kk2) {                  \
      const int row = (wn << 6) + (n4 << 4) + fr;                              \
      bF[n4][kk2] =                                                            \
          *(const bf16x8*)&Bs[bo + row * 64 + (((kk2 << 5) + ks) ^ sw)];       \
    }                                                                          \
    _Pragma("unroll") for (int ph = 0; ph < 4; ++ph) {                         \
      bf16x8 aF[2][2];                                                         \
      _Pragma("unroll") for (int mf2 = 0; mf2 < 2; ++mf2)                      \
          _Pragma("unroll") for (int kk2 = 0; kk2 < 2; ++kk2) {                \
        const int row = (wm << 7) + (((ph << 1) + mf2) << 4) + fr;             \
        aF[mf2][kk2] =                                                         \
            *(const bf16x8*)&As[bo + row * 64 + (((kk2 << 5) + ks) ^ sw)];     \
      }                                                                        \
      __builtin_amdgcn_s_setprio(1);                                           \
      _Pragma("unroll") for (int mf2 = 0; mf2 < 2; ++mf2)                      \
          _Pragma("unroll") for (int n4 = 0; n4 < 4; ++n4)                     \
              _Pragma("unroll") for (int kk2 = 0; kk2 < 2; ++kk2)              \
                  ACC[(ph << 1) + mf2][n4] =                                   \
                      __builtin_amdgcn_mfma_f32_16x16x32_bf16(                 \
                          aF[mf2][kk2], bF[n4][kk2], ACC[(ph << 1) + mf2][n4], \
                          0, 0, 0);                                            \
      __builtin_amdgcn_s_setprio(0);                                           \
    }                                                                          \
  }

// ------------------------ GEMM1 + fused local scan --------------------------
// Zb[m][c] = bf16 LOCAL-SCANNED values; partials per (chunk, colpair).
__global__ __launch_bounds__(512, 2) void gemm1_kernel(
    const unsigned short* __restrict__ xbf, const unsigned short* __restrict__ W,
    unsigned int* __restrict__ Zp, const float4* __restrict__ lamp,
    float2* __restrict__ part) {
  __shared__ unsigned short LDS[4 * 256 * 64];  // 128 KB (staging / scan buf)
  unsigned short* As = LDS;
  unsigned short* Bs = LDS + 2 * 256 * 64;
  const int tid = threadIdx.x;
  const int lane = tid & 63;
  const int w = tid >> 6;                    // 0..7
  const int wm = w >> 2, wn = w & 3;         // 2M x 4N
  const int fr = lane & 15;
  const int ks = (lane >> 4) << 3;
  const int sw = (fr & 7) << 3;              // ds_read XOR (elements)
  const int tr = tid >> 3;                   // staging row-within-64 (0..63)
  const int csw = ((tid & 7) ^ (tr & 7)) << 3;  // staging src col (elems)
  const int bsw = ((blockIdx.x & 7) << 5) + (blockIdx.x >> 3);  // XCD swizzle
  const int nt = bsw & 3, mt = bsw >> 2;     // 4 N-tiles, 64 M-tiles
  const int m0 = mt << 8, n0 = nt << 8;
  const int rb = (lane >> 4) << 2;

  f32x4 acc[8][4] = {};

  G256_STAGE(0, 0, xbf, W);
  int cur = 0;
  for (int kt = 0; kt < 15; ++kt) {
    G256_STAGE(cur ^ 1, kt + 1, xbf, W);   // next tile: stays in flight
    PIPE_PUBLISH8();
    G1_COMPUTE(cur, acc);
    PIPE_CLOSE();
    cur ^= 1;
  }
  __syncthreads();                         // final tile: full drain ok here
  G1_COMPUTE(cur, acc);

  // ---- fused scanP: spill acc -> LDS (bf16, same rounding as old Zb write)
  __syncthreads();                         // all LDS staging reads complete
  unsigned short (*SB)[256] = (unsigned short(*)[256])LDS;
#pragma unroll
  for (int mf = 0; mf < 8; ++mf)
#pragma unroll
    for (int n4 = 0; n4 < 4; ++n4) {
      const int lc = (wn << 6) + (n4 << 4) + fr;
#pragma unroll
      for (int r = 0; r < 4; ++r) {
        const int lr = (wm << 7) + (mf << 4) + rb + r;
        SB[lr][lc] = f2bf(acc[mf][n4][r]);
      }
    }
  __syncthreads();

  // one (chunk, colpair) per thread: 4 chunks x 128 colpairs = 512 tasks
  const int pp = tid & 127;                 // colpair within block
  const int ch = tid >> 7;                  // chunk within block (0..3)
  const int gcp = (n0 >> 1) + pp;           // global colpair (0..511)
  const int sdir = gcp >> 8;
  const int p = gcp & 255;
  const float4 lp = lamp[sdir * 256 + p];
  const float lre = lp.x, lim = lp.y;
  const unsigned int* SBu = (const unsigned int*)LDS;  // [256][128] u32
  const size_t growbase = (size_t)(m0 + (ch << 6));
  float sre = 0.f, sim = 0.f;
  if (sdir == 0) {
    for (int i = 0; i < 64; ++i) {
      const unsigned int u = SBu[((ch << 6) + i) * 128 + pp];
      const float nr = fmaf(lre, sre, fmaf(-lim, sim, bf2f((unsigned short)u)));
      const float ni = fmaf(lre, sim, fmaf(lim, sre, bf2f((unsigned short)(u >> 16))));
      sre = nr; sim = ni;
      Zp[(growbase + i) * 512 + gcp] =
          (unsigned int)f2bf(sre) | ((unsigned int)f2bf(sim) << 16);
    }
  } else {
    for (int i = 63; i >= 0; --i) {
      const unsigned int u = SBu[((ch << 6) + i) * 128 + pp];
      const float nr = fmaf(lre, sre, fmaf(-lim, sim, bf2f((unsigned short)u)));
      const float ni = fmaf(lre, sim, fmaf(lim, sre, bf2f((unsigned short)(u >> 16))));
      sre = nr; sim = ni;
      Zp[(growbase + i) * 512 + gcp] =
          (unsigned int)f2bf(sre) | ((unsigned int)f2bf(sim) << 16);
    }
  }
  const int b = m0 >> 12;
  const int kchunk = ((m0 & 4095) >> 6) + ch;
  const int s = b * 2 + sdir;
  part[(size_t)(s * 64 + kchunk) * 256 + p] = make_float2(sre, sim);
}

// ------------------------------- scanF --------------------------------------
// Zp holds LOCAL-SCANNED bf16 pairs. Carry inline from partials, then FIXUP:
//   fwd: xs_i = loc_i + lambda^(i+1) C;  bwd: xs_i = loc_i + lambda^(64-i) C.
__global__ __launch_bounds__(256) void scanF_kernel(
    const unsigned int* __restrict__ Zp, const float4* __restrict__ lamp,
    const float2* __restrict__ part, unsigned int* __restrict__ xsbf) {
  const int p = threadIdx.x;
  const int k = blockIdx.x & 63;
  const int s = blockIdx.x >> 6;
  const int dir = s & 1, b = s >> 1;
  const float4 lp = lamp[dir * 256 + p];
  const float lre = lp.x, lim = lp.y, wr64 = lp.z, wi64 = lp.w;
  const size_t col = (size_t)dir * 256 + p;
  const size_t mbase = (size_t)b * 4096 + (size_t)k * 64;

  // exclusive carry:
  //   fwd: C = sum_{j<k} l64^(k-1-j) S_j   (j descending, w starts at 1)
  //   bwd: C = sum_{j>k} l64^(j-k-1) S_j   (j ascending,  w starts at 1)
  float cr = 0.f, ci = 0.f, wr = 1.f, wi = 0.f;
  if (dir == 0) {
    for (int j = k - 1; j >= 0; --j) {
      const float2 S = part[(size_t)(s * 64 + j) * 256 + p];
      cr = fmaf(wr, S.x, fmaf(-wi, S.y, cr));
      ci = fmaf(wr, S.y, fmaf(wi, S.x, ci));
      const float t = wr * wr64 - wi * wi64;
      wi = wr * wi64 + wi * wr64; wr = t;
    }
  } else {
    for (int j = k + 1; j < 64; ++j) {
      const float2 S = part[(size_t)(s * 64 + j) * 256 + p];
      cr = fmaf(wr, S.x, fmaf(-wi, S.y, cr));
      ci = fmaf(wr, S.y, fmaf(wi, S.x, ci));
      const float t = wr * wr64 - wi * wi64;
      wi = wr * wi64 + wi * wr64; wr = t;
    }
  }

  // fixup walk (verbatim R10 scanC): q = lambda*C, multiply by lambda/step
  float qr = lre * cr - lim * ci;
  float qi = lre * ci + lim * cr;
  if (dir == 0) {
    for (int i = 0; i < 64; ++i) {
      const size_t idx = (mbase + i) * 512 + col;
      const unsigned int u = Zp[idx];
      const float vr = bf2f((unsigned short)u) + qr;
      const float vi = bf2f((unsigned short)(u >> 16)) + qi;
      xsbf[idx] = (unsigned int)f2bf(vr) | ((unsigned int)f2bf(vi) << 16);
      const float t = lre * qr - lim * qi;
      qi = lre * qi + lim * qr; qr = t;
    }
  } else {
    for (int i = 63; i >= 0; --i) {
      const size_t idx = (mbase + i) * 512 + col;
      const unsigned int u = Zp[idx];
      const float vr = bf2f((unsigned short)u) + qr;
      const float vi = bf2f((unsigned short)(u >> 16)) + qi;
      xsbf[idx] = (unsigned int)f2bf(vr) | ((unsigned int)f2bf(vi) << 16);
      const float t = lre * qr - lim * qi;
      qi = lre * qi + lim * qr; qr = t;
    }
  }
}

// ------------------- GEMM2 (128^2, dual acc, counted vmcnt) ------------------
#define GEMM_STAGE(BUF, KT, APTR, BPTR)                                        \
  {                                                                            \
    const int k0 = (KT) << 6;                                                  \
    _Pragma("unroll") for (int i = 0; i < 4; ++i) {                            \
      const int r = (i << 5) + tr2;                                            \
      const int o = ((BUF) << 14) + (i << 12) + (tid << 4);                    \
      gload16(APTR + (size_t)(m0 + r) * 1024 + (k0 + csw), (char*)As + o);     \
      gload16(BPTR + (size_t)(n0 + r) * 1024 + (k0 + csw), (char*)Bs + o);     \
    }                                                                          \
  }

#define GEMM_COMPUTE(BUF, ACC)                                                 \
  {                                                                            \
    const int bo = (BUF) << 13; /* element offset within As/Bs */              \
    _Pragma("unroll") for (int kk = 0; kk < 64; kk += 32) {                    \
      bf16x8 af[4], bf_[4];                                                    \
      _Pragma("unroll") for (int m4 = 0; m4 < 4; ++m4) {                       \
        const int row = (wm << 6) + (m4 << 4) + fr;                            \
        af[m4] = *(const bf16x8*)&As[bo + row * 64 + ((kk + ks) ^ sw)];        \
      }                                                                        \
      _Pragma("unroll") for (int n4 = 0; n4 < 4; ++n4) {                       \
        const int row = (wn << 6) + (n4 << 4) + fr;                            \
        bf_[n4] = *(const bf16x8*)&Bs[bo + row * 64 + ((kk + ks) ^ sw)];       \
      }                                                                        \
      _Pragma("unroll") for (int m4 = 0; m4 < 4; ++m4)                         \
          _Pragma("unroll") for (int n4 = 0; n4 < 4; ++n4)                     \
              ACC[m4][n4] = __builtin_amdgcn_mfma_f32_16x16x32_bf16(           \
                  af[m4], bf_[n4], ACC[m4][n4], 0, 0, 0);                      \
    }                                                                          \
  }

__global__ __launch_bounds__(256, 2) void gemm2_kernel(
    const unsigned short* __restrict__ A2, const unsigned short* __restrict__ CmT,
    const unsigned short* __restrict__ xbf, const float* __restrict__ Df,
    const float* __restrict__ Db, float* __restrict__ out) {
  __shared__ unsigned short As[2 * 128 * 64];
  __shared__ unsigned short Bs[2 * 128 * 64];
  const int tid = threadIdx.x;
  const int lane = tid & 63;
  const int w = tid >> 6;
  const int wm = w >> 1, wn = w & 1;
  const int fr = lane & 15;
  const int ks = (lane >> 4) << 3;
  const int sw = (fr & 7) << 3;
  const int tr2 = tid >> 3;
  const int csw = ((tid & 7) ^ (tr2 & 7)) << 3;
  const int bsw = ((blockIdx.x & 7) << 7) + (blockIdx.x >> 3);  // XCD swizzle
  const int nt = bsw & 7, mt = bsw >> 3;
  const int m0 = mt << 7, n0 = nt << 7;

  f32x4 accf[4][4] = {};
  f32x4 accb[4][4] = {};

  GEMM_STAGE(0, 0, A2, CmT);
  int cur = 0;
#pragma unroll
  for (int kt = 0; kt < 8; ++kt) {
    GEMM_STAGE(cur ^ 1, kt + 1, A2, CmT);
    PIPE_PUBLISH8();
    GEMM_COMPUTE(cur, accf);
    PIPE_CLOSE();
    cur ^= 1;
  }
#pragma unroll
  for (int kt = 8; kt < 15; ++kt) {
    GEMM_STAGE(cur ^ 1, kt + 1, A2, CmT);
    PIPE_PUBLISH8();
    GEMM_COMPUTE(cur, accb);
    PIPE_CLOSE();
    cur ^= 1;
  }
  __syncthreads();                         // final tile: full drain ok here
  GEMM_COMPUTE(cur, accb);

  const int rb = (lane >> 4) << 2;
#pragma unroll
  for (int n4 = 0; n4 < 4; ++n4) {
    const size_t gn = n0 + (wn << 6) + (n4 << 4) + fr;
    const float dfv = Df[gn], dbv = Db[gn];
#pragma unroll
    for (int m4 = 0; m4 < 4; ++m4) {
#pragma unroll
      for (int r = 0; r < 4; ++r) {
        const size_t gm = m0 + (wm << 6) + (m4 << 4) + rb + r;
        const float xv = bf2f(xbf[gm * 1024 + gn]);
        out[gm * 1024 + gn] = gelu_fast(accf[m4][n4][r] + dfv * xv) +
                              gelu_fast(accb[m4][n4][r] + dbv * xv);
      }
    }
  }
}

// ------------------------------- launch -------------------------------------
extern "C" void kernel_launch(void* const* d_in, const int* in_sizes, int n_in,
                              void* d_out, int out_size, void* d_ws, size_t ws_size,
                              hipStream_t stream) {
  const float* x = (const float*)d_in[0];
  const float* flr = (const float*)d_in[1];
  const float* fim = (const float*)d_in[2];
  const float* fBr = (const float*)d_in[3];
  const float* fBi = (const float*)d_in[4];
  const float* fCr = (const float*)d_in[5];
  const float* fCi = (const float*)d_in[6];
  const float* fD  = (const float*)d_in[7];
  const float* flD = (const float*)d_in[8];
  const float* blr = (const float*)d_in[9];
  const float* bim = (const float*)d_in[10];
  const float* bBr = (const float*)d_in[11];
  const float* bBi = (const float*)d_in[12];
  const float* bCr = (const float*)d_in[13];
  const float* bCi = (const float*)d_in[14];
  const float* bD  = (const float*)d_in[15];
  const float* blD = (const float*)d_in[16];

  char* ws = (char*)d_ws;
  unsigned short* xbf  = (unsigned short*)(ws);                  // 33,554,432
  unsigned short* W    = (unsigned short*)(ws + 33554432);       //  2,097,152
  unsigned short* CmT  = (unsigned short*)(ws + 35651584);       //  2,097,152
  unsigned short* Zb   = (unsigned short*)(ws + 37748736);       // 33,554,432
  unsigned short* xsbf = (unsigned short*)(ws + 71303168);       // 33,554,432
  float4*         lamp = (float4*)(ws + 104857600);              //      8,192
  float2*         part = (float2*)(ws + 104865792);              //  1,048,576

  cast_prep_kernel<<<9728, 256, 0, stream>>>(
      x, xbf, flr, fim, fBr, fBi, fCr, fCi, flD,
      blr, bim, bBr, bBi, bCr, bCi, blD, W, CmT, lamp);
  gemm1_kernel<<<256, 512, 0, stream>>>(xbf, W, (unsigned int*)Zb, lamp, part);
  scanF_kernel<<<512, 256, 0, stream>>>((unsigned int*)Zb, lamp, part,
                                        (unsigned int*)xsbf);
  gemm2_kernel<<<1024, 256, 0, stream>>>(xsbf, CmT, xbf, fD, bD, (float*)d_out);
}